// Round 1
// 2958.828 us; speedup vs baseline: 1.0059x; 1.0059x over previous
//
#include <hip/hip_runtime.h>
#include <cstdint>
#include <cstddef>

#define B_ 64
#define T_ 2048
#define I_ 256
#define H_ 256
#define G_ 768   // 3*H

typedef _Float16 h2v __attribute__((ext_vector_type(2)));
typedef _Float16 v8h __attribute__((ext_vector_type(8)));
typedef float    v4f __attribute__((ext_vector_type(4)));
typedef uint32_t u32x4 __attribute__((ext_vector_type(4)));

union U32h { uint32_t u; h2v h; };
__device__ __forceinline__ h2v asH(uint32_t u) { U32h t; t.u = u; return t.h; }

// ---------------------------------------------------------------------------
// prep: Whh fp32 [768][256] -> per-thread-contiguous f16-pair layout.
// Wprep[((g*2 + half)*256 + j)*64 + p] = pair(Whh[g*256+j][half*128+2p], [.. +1])
// Thread (j, half) of rec_step then loads 16 dwordx4 per gate, fully dense.
// ---------------------------------------------------------------------------
__global__ void prep_whh2(const float* __restrict__ Whh, uint32_t* __restrict__ Wprep) {
    int j = threadIdx.x;           // 0..255
    int gh = blockIdx.x;           // 0..5 = g*2 + half
    int g = gh >> 1, half = gh & 1;
    const float* src = Whh + (size_t)(g * 256 + j) * 256 + half * 128;
    uint32_t* dst = Wprep + ((size_t)gh * 256 + j) * 64;
    for (int p = 0; p < 64; ++p) {
        U32h u; u.h = h2v{(_Float16)src[2 * p], (_Float16)src[2 * p + 1]};
        dst[p] = u.u;
    }
}

// ---------------------------------------------------------------------------
// gi GEMM (unchanged): gi[t_local*64 + b][n]
// ---------------------------------------------------------------------------
#define LDA 56
#define LDB 56

__launch_bounds__(256, 2)
__global__ void gemm_gi(const float* __restrict__ x, const float* __restrict__ Wih,
                        const float* __restrict__ bih, _Float16* __restrict__ gi,
                        int t0) {
    __shared__ __align__(16) _Float16 As[64 * LDA];
    __shared__ __align__(16) _Float16 Bs[384 * LDB];
    int tid  = threadIdx.x;
    int t    = t0 + blockIdx.x;
    int n0   = blockIdx.y * 384;
    int lane = tid & 63, wave = tid >> 6;
    int quad = lane >> 4, r16 = lane & 15;

    v4f acc[24];
#pragma unroll
    for (int i = 0; i < 24; ++i) acc[i] = v4f{0.f, 0.f, 0.f, 0.f};

    for (int ki = 0; ki < 8; ++ki) {
        int k0 = ki * 32;
        __syncthreads();
#pragma unroll
        for (int s = 0; s < 2; ++s) {
            int slot = tid + s * 256;
            int row = slot >> 3;
            int part = slot & 7;
            const float* xp = x + ((size_t)row * T_ + t) * I_ + k0 + part * 4;
            float4 v = *(const float4*)xp;
            U32h u0, u1;
            u0.h = h2v{(_Float16)v.x, (_Float16)v.y};
            u1.h = h2v{(_Float16)v.z, (_Float16)v.w};
            uint32_t* dst = (uint32_t*)&As[row * LDA + part * 4];
            dst[0] = u0.u; dst[1] = u1.u;
        }
#pragma unroll
        for (int s = 0; s < 12; ++s) {
            int slot = tid + s * 256;
            int row = slot >> 3;
            int part = slot & 7;
            const float* wp = Wih + (size_t)(n0 + row) * I_ + k0 + part * 4;
            float4 v = *(const float4*)wp;
            U32h u0, u1;
            u0.h = h2v{(_Float16)v.x, (_Float16)v.y};
            u1.h = h2v{(_Float16)v.z, (_Float16)v.w};
            uint32_t* dst = (uint32_t*)&Bs[row * LDB + part * 4];
            dst[0] = u0.u; dst[1] = u1.u;
        }
        __syncthreads();
        v8h af = *(const v8h*)&As[(wave * 16 + r16) * LDA + quad * 8];
#pragma unroll
        for (int nt = 0; nt < 24; ++nt) {
            v8h bf = *(const v8h*)&Bs[(nt * 16 + r16) * LDB + quad * 8];
            acc[nt] = __builtin_amdgcn_mfma_f32_16x16x32_f16(af, bf, acc[nt], 0, 0, 0);
        }
    }
#pragma unroll
    for (int nt = 0; nt < 24; ++nt) {
        int n = n0 + nt * 16 + r16;
        float bias = bih[n];
#pragma unroll
        for (int reg = 0; reg < 4; ++reg) {
            int m = wave * 16 + quad * 4 + reg;
            size_t off = ((size_t)blockIdx.x * 64 + m) * G_ + n;
            gi[off] = (_Float16)(acc[nt][reg] + bias);
        }
    }
}

// ---------------------------------------------------------------------------
// Recurrent kernel v3: one block of 512 threads per batch element.
// Thread (j = tid&255, half = tid>>8) computes half-dots (k in
// [half*128, half*128+128)) for gates 0..2 of column j.
//
// CHANGE vs v2: the 192 weight dwords per thread are PINNED in VGPRs via an
// opaque asm "+v" pass-through after the preload. v2's VGPR_Count=116 proved
// the compiler rematerialized the (loop-invariant) weight loads into the
// t-loop -> 393 KB/block/step re-streamed from L2 (~3070 cyc/step at
// ~128 B/cyc/CU, matching the measured 2920 cyc/step). An asm result cannot
// be rematerialized, so the allocator must keep all 192 live (fits: cap is
// 256 VGPRs at 2 waves/SIMD per __launch_bounds__(512,2)). Weight arrays are
// scalar uint32_t[64] with static indices only (SROA-safe).
// ---------------------------------------------------------------------------
__launch_bounds__(512, 2)
__global__ void rec_step(const uint32_t* __restrict__ Wprep, const float* __restrict__ bhh,
                         const _Float16* __restrict__ gi, const float* __restrict__ h_init,
                         float* __restrict__ out, float* __restrict__ hN,
                         float* __restrict__ h_carry, int t0, int len) {
    __shared__ __align__(16) _Float16 hb[2][256];
    __shared__ float part[2][3][256];   // [half][gate][j]

    int b = blockIdx.x;
    int tid = threadIdx.x;
    int j = tid & 255, half = tid >> 8;

    // ---- load weights into registers: 3 gates x 64 dwords ----
    uint32_t w0[64], w1[64], w2[64];
    {
        const u32x4* wp0 = (const u32x4*)(Wprep + ((size_t)(0 + half) * 256 + j) * 64);
        const u32x4* wp1 = (const u32x4*)(Wprep + ((size_t)(2 + half) * 256 + j) * 64);
        const u32x4* wp2 = (const u32x4*)(Wprep + ((size_t)(4 + half) * 256 + j) * 64);
#pragma unroll
        for (int p = 0; p < 16; ++p) {
            u32x4 v0 = wp0[p];
            w0[4 * p + 0] = v0[0]; w0[4 * p + 1] = v0[1];
            w0[4 * p + 2] = v0[2]; w0[4 * p + 3] = v0[3];
        }
#pragma unroll
        for (int p = 0; p < 16; ++p) {
            u32x4 v1 = wp1[p];
            w1[4 * p + 0] = v1[0]; w1[4 * p + 1] = v1[1];
            w1[4 * p + 2] = v1[2]; w1[4 * p + 3] = v1[3];
        }
#pragma unroll
        for (int p = 0; p < 16; ++p) {
            u32x4 v2 = wp2[p];
            w2[4 * p + 0] = v2[0]; w2[4 * p + 1] = v2[1];
            w2[4 * p + 2] = v2[2]; w2[4 * p + 3] = v2[3];
        }
    }
    // ---- pin: opaque asm kills rematerialization of the loads above ----
#pragma unroll
    for (int i = 0; i < 64; ++i) {
        asm volatile("" : "+v"(w0[i]));
        asm volatile("" : "+v"(w1[i]));
        asm volatile("" : "+v"(w2[i]));
    }

    // ---- pointwise-thread state (tid < 256) ----
    float bh0 = 0.f, bh1 = 0.f, bh2 = 0.f, hprev = 0.f;
    float g0 = 0.f, g1 = 0.f, g2 = 0.f;
    const _Float16* gp = gi + (size_t)b * G_ + j;
    float* outp = out + (size_t)b * T_ * H_ + (size_t)t0 * H_ + j;
    if (tid < 256) {
        bh0 = bhh[j]; bh1 = bhh[256 + j]; bh2 = bhh[512 + j];
        hprev = h_init[b * 256 + j];
        hb[0][j] = (_Float16)hprev;
        g0 = (float)gp[0]; g1 = (float)gp[256]; g2 = (float)gp[512];
    }
    __syncthreads();

    int cur = 0;
    for (int t = 0; t < len; ++t) {
        // prefetch next step's gi (consumed after the dot phase)
        float p0 = 0.f, p1 = 0.f, p2 = 0.f;
        if (tid < 256 && t + 1 < len) {
            const _Float16* gq = gp + (size_t)(t + 1) * B_ * G_;
            p0 = (float)gq[0]; p1 = (float)gq[256]; p2 = (float)gq[512];
        }

        // ---- dot phase: 16 x (1 broadcast ds_read_b128 + 12 fdot2) ----
        float a0 = 0.f, a1 = 0.f, a2 = 0.f;
        const u32x4* hv4 = (const u32x4*)&hb[cur][half * 128];
#pragma unroll
        for (int p4 = 0; p4 < 16; ++p4) {
            u32x4 hv = hv4[p4];
#pragma unroll
            for (int q = 0; q < 4; ++q) {
                h2v hq = asH(hv[q]);
                a0 = __builtin_amdgcn_fdot2(asH(w0[4 * p4 + q]), hq, a0, false);
                a1 = __builtin_amdgcn_fdot2(asH(w1[4 * p4 + q]), hq, a1, false);
                a2 = __builtin_amdgcn_fdot2(asH(w2[4 * p4 + q]), hq, a2, false);
            }
        }
        part[half][0][j] = a0;
        part[half][1][j] = a1;
        part[half][2][j] = a2;
        __syncthreads();

        // ---- pointwise phase ----
        if (tid < 256) {
            float s0 = part[0][0][j] + part[1][0][j] + bh0;
            float s1 = part[0][1][j] + part[1][1][j] + bh1;
            float s2 = part[0][2][j] + part[1][2][j] + bh2;
            float r = 1.f / (1.f + __expf(-(g0 + s0)));
            float u = 1.f / (1.f + __expf(-(g2 + s2)));
            float carg = g1 + r * s1;
            carg = fminf(fmaxf(carg, -20.f), 20.f);
            float e2 = __expf(2.f * carg);
            float n = (e2 - 1.f) / (e2 + 1.f);
            float hnew = hprev + u * (n - hprev);
            outp[(size_t)t * H_] = hnew;
            hb[cur ^ 1][j] = (_Float16)hnew;
            hprev = hnew;
            g0 = p0; g1 = p1; g2 = p2;
        }
        __syncthreads();
        cur ^= 1;
    }
    if (tid < 256) {
        h_carry[b * 256 + j] = hprev;
        if (t0 + len == T_) hN[b * 256 + j] = hprev;
    }
}

// ---------------------------------------------------------------------------
extern "C" void kernel_launch(void* const* d_in, const int* in_sizes, int n_in,
                              void* d_out, int out_size, void* d_ws, size_t ws_size,
                              hipStream_t stream) {
    const float* x   = (const float*)d_in[0];
    const float* h0  = (const float*)d_in[1];
    const float* Wih = (const float*)d_in[2];
    const float* bih = (const float*)d_in[3];
    const float* Whh = (const float*)d_in[4];
    const float* bhh = (const float*)d_in[5];
    float* out = (float*)d_out;
    float* hN  = out + (size_t)B_ * T_ * H_;

    char* ws = (char*)d_ws;
    float*    h_carry = (float*)ws;                       // 65536 B
    uint32_t* Wprep   = (uint32_t*)(ws + 65536);          // 393216 B
    _Float16* gi      = (_Float16*)(ws + 65536 + 393216);

    const size_t head = 65536 + 393216;
    const size_t per_t = (size_t)B_ * G_ * sizeof(_Float16);  // 98304 B
    size_t avail = (ws_size > head) ? (ws_size - head) : 0;
    int tc = (int)(avail / per_t);
    if (tc > T_) tc = T_;
    if (tc < 1)  tc = 1;
    int nch = (T_ + tc - 1) / tc;
    tc = (T_ + nch - 1) / nch;

    hipLaunchKernelGGL(prep_whh2, dim3(6), dim3(256), 0, stream, Whh, Wprep);
    for (int t0 = 0; t0 < T_; t0 += tc) {
        int len = (T_ - t0 < tc) ? (T_ - t0) : tc;
        hipLaunchKernelGGL(gemm_gi, dim3(len, 2), dim3(256), 0, stream,
                           x, Wih, bih, gi, t0);
        const float* hi = (t0 == 0) ? h0 : h_carry;
        hipLaunchKernelGGL(rec_step, dim3(64), dim3(512), 0, stream,
                           Wprep, bhh, gi, hi, out, hN, h_carry, t0, len);
    }
}

// Round 2
// 2957.810 us; speedup vs baseline: 1.0063x; 1.0003x over previous
//
#include <hip/hip_runtime.h>
#include <cstdint>
#include <cstddef>

#define B_ 64
#define T_ 2048
#define I_ 256
#define H_ 256
#define G_ 768   // 3*H

typedef _Float16 h2v __attribute__((ext_vector_type(2)));
typedef _Float16 v8h __attribute__((ext_vector_type(8)));
typedef float    v4f __attribute__((ext_vector_type(4)));
typedef uint32_t u32x4 __attribute__((ext_vector_type(4)));

union U32h { uint32_t u; h2v h; };
__device__ __forceinline__ h2v asH(uint32_t u) { U32h t; t.u = u; return t.h; }

// ---------------------------------------------------------------------------
// prep: Whh fp32 [768][256] -> per-thread-contiguous f16-pair layout.
// Wprep[((g*2 + half)*256 + j)*64 + p] = pair(Whh[g*256+j][half*128+2p], [.. +1])
// Thread (j, half) of rec_step then loads 16 dwordx4 per gate, fully dense.
// ---------------------------------------------------------------------------
__global__ void prep_whh2(const float* __restrict__ Whh, uint32_t* __restrict__ Wprep) {
    int j = threadIdx.x;           // 0..255
    int gh = blockIdx.x;           // 0..5 = g*2 + half
    int g = gh >> 1, half = gh & 1;
    const float* src = Whh + (size_t)(g * 256 + j) * 256 + half * 128;
    uint32_t* dst = Wprep + ((size_t)gh * 256 + j) * 64;
    for (int p = 0; p < 64; ++p) {
        U32h u; u.h = h2v{(_Float16)src[2 * p], (_Float16)src[2 * p + 1]};
        dst[p] = u.u;
    }
}

// ---------------------------------------------------------------------------
// gi GEMM (unchanged): gi[t_local*64 + b][n]
// ---------------------------------------------------------------------------
#define LDA 56
#define LDB 56

__launch_bounds__(256, 2)
__global__ void gemm_gi(const float* __restrict__ x, const float* __restrict__ Wih,
                        const float* __restrict__ bih, _Float16* __restrict__ gi,
                        int t0) {
    __shared__ __align__(16) _Float16 As[64 * LDA];
    __shared__ __align__(16) _Float16 Bs[384 * LDB];
    int tid  = threadIdx.x;
    int t    = t0 + blockIdx.x;
    int n0   = blockIdx.y * 384;
    int lane = tid & 63, wave = tid >> 6;
    int quad = lane >> 4, r16 = lane & 15;

    v4f acc[24];
#pragma unroll
    for (int i = 0; i < 24; ++i) acc[i] = v4f{0.f, 0.f, 0.f, 0.f};

    for (int ki = 0; ki < 8; ++ki) {
        int k0 = ki * 32;
        __syncthreads();
#pragma unroll
        for (int s = 0; s < 2; ++s) {
            int slot = tid + s * 256;
            int row = slot >> 3;
            int part = slot & 7;
            const float* xp = x + ((size_t)row * T_ + t) * I_ + k0 + part * 4;
            float4 v = *(const float4*)xp;
            U32h u0, u1;
            u0.h = h2v{(_Float16)v.x, (_Float16)v.y};
            u1.h = h2v{(_Float16)v.z, (_Float16)v.w};
            uint32_t* dst = (uint32_t*)&As[row * LDA + part * 4];
            dst[0] = u0.u; dst[1] = u1.u;
        }
#pragma unroll
        for (int s = 0; s < 12; ++s) {
            int slot = tid + s * 256;
            int row = slot >> 3;
            int part = slot & 7;
            const float* wp = Wih + (size_t)(n0 + row) * I_ + k0 + part * 4;
            float4 v = *(const float4*)wp;
            U32h u0, u1;
            u0.h = h2v{(_Float16)v.x, (_Float16)v.y};
            u1.h = h2v{(_Float16)v.z, (_Float16)v.w};
            uint32_t* dst = (uint32_t*)&Bs[row * LDB + part * 4];
            dst[0] = u0.u; dst[1] = u1.u;
        }
        __syncthreads();
        v8h af = *(const v8h*)&As[(wave * 16 + r16) * LDA + quad * 8];
#pragma unroll
        for (int nt = 0; nt < 24; ++nt) {
            v8h bf = *(const v8h*)&Bs[(nt * 16 + r16) * LDB + quad * 8];
            acc[nt] = __builtin_amdgcn_mfma_f32_16x16x32_f16(af, bf, acc[nt], 0, 0, 0);
        }
    }
#pragma unroll
    for (int nt = 0; nt < 24; ++nt) {
        int n = n0 + nt * 16 + r16;
        float bias = bih[n];
#pragma unroll
        for (int reg = 0; reg < 4; ++reg) {
            int m = wave * 16 + quad * 4 + reg;
            size_t off = ((size_t)blockIdx.x * 64 + m) * G_ + n;
            gi[off] = (_Float16)(acc[nt][reg] + bias);
        }
    }
}

// ---------------------------------------------------------------------------
// Recurrent kernel v4: one block of 512 threads per batch element.
// Thread (j = tid&255, half = tid>>8) computes half-dots (k in
// [half*128, half*128+128)) for gates 0..2 of column j.
//
// CHANGE vs v3: occupancy target set explicitly with amdgpu_waves_per_eu(1,2).
// v3's VGPR_Count=116 (<=128) showed the backend targeted 4 waves/EU despite
// __launch_bounds__(512,2), spilling all 192 weight dwords to scratch -> the
// in-loop scratch/L2 reloads (393 KB/block/step at ~307 GB/s per-CU L2 BW)
// are the measured 1.21 us/step. Extra occupancy is worthless here: 64 blocks
// on 256 CUs = 1 block/CU regardless. min=1 raises the VGPR budget to 512;
// max=2 tells the scheduler NOT to spill chasing 4 waves/EU. The asm pin
// stays as anti-remat/anti-LICM insurance. Weight arrays are scalar
// uint32_t[64] with static indices only (SROA-safe).
// ---------------------------------------------------------------------------
__global__ void __launch_bounds__(512)
__attribute__((amdgpu_waves_per_eu(1, 2)))
rec_step(const uint32_t* __restrict__ Wprep, const float* __restrict__ bhh,
         const _Float16* __restrict__ gi, const float* __restrict__ h_init,
         float* __restrict__ out, float* __restrict__ hN,
         float* __restrict__ h_carry, int t0, int len) {
    __shared__ __align__(16) _Float16 hb[2][256];
    __shared__ float part[2][3][256];   // [half][gate][j]

    int b = blockIdx.x;
    int tid = threadIdx.x;
    int j = tid & 255, half = tid >> 8;

    // ---- load weights into registers: 3 gates x 64 dwords ----
    uint32_t w0[64], w1[64], w2[64];
    {
        const u32x4* wp0 = (const u32x4*)(Wprep + ((size_t)(0 + half) * 256 + j) * 64);
        const u32x4* wp1 = (const u32x4*)(Wprep + ((size_t)(2 + half) * 256 + j) * 64);
        const u32x4* wp2 = (const u32x4*)(Wprep + ((size_t)(4 + half) * 256 + j) * 64);
#pragma unroll
        for (int p = 0; p < 16; ++p) {
            u32x4 v0 = wp0[p];
            w0[4 * p + 0] = v0[0]; w0[4 * p + 1] = v0[1];
            w0[4 * p + 2] = v0[2]; w0[4 * p + 3] = v0[3];
        }
#pragma unroll
        for (int p = 0; p < 16; ++p) {
            u32x4 v1 = wp1[p];
            w1[4 * p + 0] = v1[0]; w1[4 * p + 1] = v1[1];
            w1[4 * p + 2] = v1[2]; w1[4 * p + 3] = v1[3];
        }
#pragma unroll
        for (int p = 0; p < 16; ++p) {
            u32x4 v2 = wp2[p];
            w2[4 * p + 0] = v2[0]; w2[4 * p + 1] = v2[1];
            w2[4 * p + 2] = v2[2]; w2[4 * p + 3] = v2[3];
        }
    }
    // ---- pin: opaque asm kills rematerialization of the loads above ----
#pragma unroll
    for (int i = 0; i < 64; ++i) {
        asm volatile("" : "+v"(w0[i]));
        asm volatile("" : "+v"(w1[i]));
        asm volatile("" : "+v"(w2[i]));
    }

    // ---- pointwise-thread state (tid < 256) ----
    float bh0 = 0.f, bh1 = 0.f, bh2 = 0.f, hprev = 0.f;
    float g0 = 0.f, g1 = 0.f, g2 = 0.f;
    const _Float16* gp = gi + (size_t)b * G_ + j;
    float* outp = out + (size_t)b * T_ * H_ + (size_t)t0 * H_ + j;
    if (tid < 256) {
        bh0 = bhh[j]; bh1 = bhh[256 + j]; bh2 = bhh[512 + j];
        hprev = h_init[b * 256 + j];
        hb[0][j] = (_Float16)hprev;
        g0 = (float)gp[0]; g1 = (float)gp[256]; g2 = (float)gp[512];
    }
    __syncthreads();

    int cur = 0;
    for (int t = 0; t < len; ++t) {
        // prefetch next step's gi (consumed after the dot phase)
        float p0 = 0.f, p1 = 0.f, p2 = 0.f;
        if (tid < 256 && t + 1 < len) {
            const _Float16* gq = gp + (size_t)(t + 1) * B_ * G_;
            p0 = (float)gq[0]; p1 = (float)gq[256]; p2 = (float)gq[512];
        }

        // ---- dot phase: 16 x (1 broadcast ds_read_b128 + 12 fdot2) ----
        float a0 = 0.f, a1 = 0.f, a2 = 0.f;
        const u32x4* hv4 = (const u32x4*)&hb[cur][half * 128];
#pragma unroll
        for (int p4 = 0; p4 < 16; ++p4) {
            u32x4 hv = hv4[p4];
#pragma unroll
            for (int q = 0; q < 4; ++q) {
                h2v hq = asH(hv[q]);
                a0 = __builtin_amdgcn_fdot2(asH(w0[4 * p4 + q]), hq, a0, false);
                a1 = __builtin_amdgcn_fdot2(asH(w1[4 * p4 + q]), hq, a1, false);
                a2 = __builtin_amdgcn_fdot2(asH(w2[4 * p4 + q]), hq, a2, false);
            }
        }
        part[half][0][j] = a0;
        part[half][1][j] = a1;
        part[half][2][j] = a2;
        __syncthreads();

        // ---- pointwise phase ----
        if (tid < 256) {
            float s0 = part[0][0][j] + part[1][0][j] + bh0;
            float s1 = part[0][1][j] + part[1][1][j] + bh1;
            float s2 = part[0][2][j] + part[1][2][j] + bh2;
            float r = 1.f / (1.f + __expf(-(g0 + s0)));
            float u = 1.f / (1.f + __expf(-(g2 + s2)));
            float carg = g1 + r * s1;
            carg = fminf(fmaxf(carg, -20.f), 20.f);
            float e2 = __expf(2.f * carg);
            float n = (e2 - 1.f) / (e2 + 1.f);
            float hnew = hprev + u * (n - hprev);
            outp[(size_t)t * H_] = hnew;
            hb[cur ^ 1][j] = (_Float16)hnew;
            hprev = hnew;
            g0 = p0; g1 = p1; g2 = p2;
        }
        __syncthreads();
        cur ^= 1;
    }
    if (tid < 256) {
        h_carry[b * 256 + j] = hprev;
        if (t0 + len == T_) hN[b * 256 + j] = hprev;
    }
}

// ---------------------------------------------------------------------------
extern "C" void kernel_launch(void* const* d_in, const int* in_sizes, int n_in,
                              void* d_out, int out_size, void* d_ws, size_t ws_size,
                              hipStream_t stream) {
    const float* x   = (const float*)d_in[0];
    const float* h0  = (const float*)d_in[1];
    const float* Wih = (const float*)d_in[2];
    const float* bih = (const float*)d_in[3];
    const float* Whh = (const float*)d_in[4];
    const float* bhh = (const float*)d_in[5];
    float* out = (float*)d_out;
    float* hN  = out + (size_t)B_ * T_ * H_;

    char* ws = (char*)d_ws;
    float*    h_carry = (float*)ws;                       // 65536 B
    uint32_t* Wprep   = (uint32_t*)(ws + 65536);          // 393216 B
    _Float16* gi      = (_Float16*)(ws + 65536 + 393216);

    const size_t head = 65536 + 393216;
    const size_t per_t = (size_t)B_ * G_ * sizeof(_Float16);  // 98304 B
    size_t avail = (ws_size > head) ? (ws_size - head) : 0;
    int tc = (int)(avail / per_t);
    if (tc > T_) tc = T_;
    if (tc < 1)  tc = 1;
    int nch = (T_ + tc - 1) / tc;
    tc = (T_ + nch - 1) / nch;

    hipLaunchKernelGGL(prep_whh2, dim3(6), dim3(256), 0, stream, Whh, Wprep);
    for (int t0 = 0; t0 < T_; t0 += tc) {
        int len = (T_ - t0 < tc) ? (T_ - t0) : tc;
        hipLaunchKernelGGL(gemm_gi, dim3(len, 2), dim3(256), 0, stream,
                           x, Wih, bih, gi, t0);
        const float* hi = (t0 == 0) ? h0 : h_carry;
        hipLaunchKernelGGL(rec_step, dim3(64), dim3(512), 0, stream,
                           Wprep, bhh, gi, hi, out, hN, h_carry, t0, len);
    }
}

// Round 3
// 2862.802 us; speedup vs baseline: 1.0397x; 1.0332x over previous
//
#include <hip/hip_runtime.h>
#include <cstdint>
#include <cstddef>

#define B_ 64
#define T_ 2048
#define I_ 256
#define H_ 256
#define G_ 768   // 3*H

typedef _Float16 h2v __attribute__((ext_vector_type(2)));
typedef _Float16 v8h __attribute__((ext_vector_type(8)));
typedef float    v4f __attribute__((ext_vector_type(4)));
typedef uint32_t u32x4 __attribute__((ext_vector_type(4)));

union U32h { uint32_t u; h2v h; };
__device__ __forceinline__ h2v asH(uint32_t u) { U32h t; t.u = u; return t.h; }

// ---------------------------------------------------------------------------
// prep: Whh fp32 [768][256] -> per-thread-contiguous f16-pair layout, QUARTER
// granularity. Wprep[((g*4 + q)*256 + j)*32 + p] =
//   pair(Whh[g*256+j][q*64+2p], Whh[g*256+j][q*64+2p+1])
// Thread (j, q) of rec_step loads 8 dwordx4 per gate, fully dense.
// ---------------------------------------------------------------------------
__global__ void prep_whh4(const float* __restrict__ Whh, uint32_t* __restrict__ Wprep) {
    int j = threadIdx.x;           // 0..255
    int gq = blockIdx.x;           // 0..11 = g*4 + q
    int g = gq >> 2, q = gq & 3;
    const float* src = Whh + (size_t)(g * 256 + j) * 256 + q * 64;
    uint32_t* dst = Wprep + ((size_t)gq * 256 + j) * 32;
    for (int p = 0; p < 32; ++p) {
        U32h u; u.h = h2v{(_Float16)src[2 * p], (_Float16)src[2 * p + 1]};
        dst[p] = u.u;
    }
}

// ---------------------------------------------------------------------------
// gi GEMM (unchanged): gi[t_local*64 + b][n]
// ---------------------------------------------------------------------------
#define LDA 56
#define LDB 56

__launch_bounds__(256, 2)
__global__ void gemm_gi(const float* __restrict__ x, const float* __restrict__ Wih,
                        const float* __restrict__ bih, _Float16* __restrict__ gi,
                        int t0) {
    __shared__ __align__(16) _Float16 As[64 * LDA];
    __shared__ __align__(16) _Float16 Bs[384 * LDB];
    int tid  = threadIdx.x;
    int t    = t0 + blockIdx.x;
    int n0   = blockIdx.y * 384;
    int lane = tid & 63, wave = tid >> 6;
    int quad = lane >> 4, r16 = lane & 15;

    v4f acc[24];
#pragma unroll
    for (int i = 0; i < 24; ++i) acc[i] = v4f{0.f, 0.f, 0.f, 0.f};

    for (int ki = 0; ki < 8; ++ki) {
        int k0 = ki * 32;
        __syncthreads();
#pragma unroll
        for (int s = 0; s < 2; ++s) {
            int slot = tid + s * 256;
            int row = slot >> 3;
            int part = slot & 7;
            const float* xp = x + ((size_t)row * T_ + t) * I_ + k0 + part * 4;
            float4 v = *(const float4*)xp;
            U32h u0, u1;
            u0.h = h2v{(_Float16)v.x, (_Float16)v.y};
            u1.h = h2v{(_Float16)v.z, (_Float16)v.w};
            uint32_t* dst = (uint32_t*)&As[row * LDA + part * 4];
            dst[0] = u0.u; dst[1] = u1.u;
        }
#pragma unroll
        for (int s = 0; s < 12; ++s) {
            int slot = tid + s * 256;
            int row = slot >> 3;
            int part = slot & 7;
            const float* wp = Wih + (size_t)(n0 + row) * I_ + k0 + part * 4;
            float4 v = *(const float4*)wp;
            U32h u0, u1;
            u0.h = h2v{(_Float16)v.x, (_Float16)v.y};
            u1.h = h2v{(_Float16)v.z, (_Float16)v.w};
            uint32_t* dst = (uint32_t*)&Bs[row * LDB + part * 4];
            dst[0] = u0.u; dst[1] = u1.u;
        }
        __syncthreads();
        v8h af = *(const v8h*)&As[(wave * 16 + r16) * LDA + quad * 8];
#pragma unroll
        for (int nt = 0; nt < 24; ++nt) {
            v8h bf = *(const v8h*)&Bs[(nt * 16 + r16) * LDB + quad * 8];
            acc[nt] = __builtin_amdgcn_mfma_f32_16x16x32_f16(af, bf, acc[nt], 0, 0, 0);
        }
    }
#pragma unroll
    for (int nt = 0; nt < 24; ++nt) {
        int n = n0 + nt * 16 + r16;
        float bias = bih[n];
#pragma unroll
        for (int reg = 0; reg < 4; ++reg) {
            int m = wave * 16 + quad * 4 + reg;
            size_t off = ((size_t)blockIdx.x * 64 + m) * G_ + n;
            gi[off] = (_Float16)(acc[nt][reg] + bias);
        }
    }
}

// ---------------------------------------------------------------------------
// Recurrent kernel v5: one block of 1024 threads per batch element.
// Thread (j = tid&255, q = tid>>8) computes QUARTER-dots (k in
// [q*64, q*64+64)) for gates 0..2 of column j -> 96 weight dwords/thread.
//
// WHY 1024 threads: v3/v4 proved the backend caps this kernel at ~116-128
// VGPRs regardless of launch_bounds/waves_per_eu hints; 192 weight dwords
// per thread were spilled and re-streamed from L2 every step (393 KB/block
// /step at ~134 B/cyc/CU = the measured 2920 cyc/step). At 96 dwords/thread
// the worst-case live set (~118) fits UNDER the 128-reg budget the compiler
// demonstrably targets, so there is nothing to spill. Total fdot2 issue is
// conserved (96 x 4 waves/SIMD = 192 x 2). h-reads from LDS remain
// same-address broadcasts (free).
// ---------------------------------------------------------------------------
__global__ void __launch_bounds__(1024, 4)
rec_step(const uint32_t* __restrict__ Wprep, const float* __restrict__ bhh,
         const _Float16* __restrict__ gi, const float* __restrict__ h_init,
         float* __restrict__ out, float* __restrict__ hN,
         float* __restrict__ h_carry, int t0, int len) {
    __shared__ __align__(16) _Float16 hb[2][256];
    __shared__ float part[4][3][256];   // [quarter][gate][j]

    int b = blockIdx.x;
    int tid = threadIdx.x;
    int j = tid & 255, q = tid >> 8;

    // ---- load weights into registers: 3 gates x 32 dwords ----
    uint32_t w0[32], w1[32], w2[32];
    {
        const u32x4* wp0 = (const u32x4*)(Wprep + ((size_t)(0 * 4 + q) * 256 + j) * 32);
        const u32x4* wp1 = (const u32x4*)(Wprep + ((size_t)(1 * 4 + q) * 256 + j) * 32);
        const u32x4* wp2 = (const u32x4*)(Wprep + ((size_t)(2 * 4 + q) * 256 + j) * 32);
#pragma unroll
        for (int p = 0; p < 8; ++p) {
            u32x4 v0 = wp0[p];
            w0[4 * p + 0] = v0[0]; w0[4 * p + 1] = v0[1];
            w0[4 * p + 2] = v0[2]; w0[4 * p + 3] = v0[3];
        }
#pragma unroll
        for (int p = 0; p < 8; ++p) {
            u32x4 v1 = wp1[p];
            w1[4 * p + 0] = v1[0]; w1[4 * p + 1] = v1[1];
            w1[4 * p + 2] = v1[2]; w1[4 * p + 3] = v1[3];
        }
#pragma unroll
        for (int p = 0; p < 8; ++p) {
            u32x4 v2 = wp2[p];
            w2[4 * p + 0] = v2[0]; w2[4 * p + 1] = v2[1];
            w2[4 * p + 2] = v2[2]; w2[4 * p + 3] = v2[3];
        }
    }
    // ---- pin: opaque asm kills rematerialization of the loads above ----
#pragma unroll
    for (int i = 0; i < 32; ++i) {
        asm volatile("" : "+v"(w0[i]));
        asm volatile("" : "+v"(w1[i]));
        asm volatile("" : "+v"(w2[i]));
    }

    // ---- pointwise-thread state (tid < 256) ----
    float bh0 = 0.f, bh1 = 0.f, bh2 = 0.f, hprev = 0.f;
    float g0 = 0.f, g1 = 0.f, g2 = 0.f;
    const _Float16* gp = gi + (size_t)b * G_ + j;
    float* outp = out + (size_t)b * T_ * H_ + (size_t)t0 * H_ + j;
    if (tid < 256) {
        bh0 = bhh[j]; bh1 = bhh[256 + j]; bh2 = bhh[512 + j];
        hprev = h_init[b * 256 + j];
        hb[0][j] = (_Float16)hprev;
        g0 = (float)gp[0]; g1 = (float)gp[256]; g2 = (float)gp[512];
    }
    __syncthreads();

    int cur = 0;
    for (int t = 0; t < len; ++t) {
        // prefetch next step's gi (consumed after the dot phase)
        float p0 = 0.f, p1 = 0.f, p2 = 0.f;
        if (tid < 256 && t + 1 < len) {
            const _Float16* gq = gp + (size_t)(t + 1) * B_ * G_;
            p0 = (float)gq[0]; p1 = (float)gq[256]; p2 = (float)gq[512];
        }

        // ---- dot phase: 8 x (1 broadcast ds_read_b128 + 12 fdot2) ----
        float a0 = 0.f, a1 = 0.f, a2 = 0.f;
        const u32x4* hv4 = (const u32x4*)&hb[cur][q * 64];
#pragma unroll
        for (int p4 = 0; p4 < 8; ++p4) {
            u32x4 hv = hv4[p4];
#pragma unroll
            for (int qq = 0; qq < 4; ++qq) {
                h2v hq = asH(hv[qq]);
                a0 = __builtin_amdgcn_fdot2(asH(w0[4 * p4 + qq]), hq, a0, false);
                a1 = __builtin_amdgcn_fdot2(asH(w1[4 * p4 + qq]), hq, a1, false);
                a2 = __builtin_amdgcn_fdot2(asH(w2[4 * p4 + qq]), hq, a2, false);
            }
        }
        part[q][0][j] = a0;
        part[q][1][j] = a1;
        part[q][2][j] = a2;
        __syncthreads();

        // ---- pointwise phase ----
        if (tid < 256) {
            float s0 = part[0][0][j] + part[1][0][j] + part[2][0][j] + part[3][0][j] + bh0;
            float s1 = part[0][1][j] + part[1][1][j] + part[2][1][j] + part[3][1][j] + bh1;
            float s2 = part[0][2][j] + part[1][2][j] + part[2][2][j] + part[3][2][j] + bh2;
            float r = 1.f / (1.f + __expf(-(g0 + s0)));
            float u = 1.f / (1.f + __expf(-(g2 + s2)));
            float carg = g1 + r * s1;
            carg = fminf(fmaxf(carg, -20.f), 20.f);
            float e2 = __expf(2.f * carg);
            float n = (e2 - 1.f) / (e2 + 1.f);
            float hnew = hprev + u * (n - hprev);
            outp[(size_t)t * H_] = hnew;
            hb[cur ^ 1][j] = (_Float16)hnew;
            hprev = hnew;
            g0 = p0; g1 = p1; g2 = p2;
        }
        __syncthreads();
        cur ^= 1;
    }
    if (tid < 256) {
        h_carry[b * 256 + j] = hprev;
        if (t0 + len == T_) hN[b * 256 + j] = hprev;
    }
}

// ---------------------------------------------------------------------------
extern "C" void kernel_launch(void* const* d_in, const int* in_sizes, int n_in,
                              void* d_out, int out_size, void* d_ws, size_t ws_size,
                              hipStream_t stream) {
    const float* x   = (const float*)d_in[0];
    const float* h0  = (const float*)d_in[1];
    const float* Wih = (const float*)d_in[2];
    const float* bih = (const float*)d_in[3];
    const float* Whh = (const float*)d_in[4];
    const float* bhh = (const float*)d_in[5];
    float* out = (float*)d_out;
    float* hN  = out + (size_t)B_ * T_ * H_;

    char* ws = (char*)d_ws;
    float*    h_carry = (float*)ws;                       // 65536 B
    uint32_t* Wprep   = (uint32_t*)(ws + 65536);          // 393216 B
    _Float16* gi      = (_Float16*)(ws + 65536 + 393216);

    const size_t head = 65536 + 393216;
    const size_t per_t = (size_t)B_ * G_ * sizeof(_Float16);  // 98304 B
    size_t avail = (ws_size > head) ? (ws_size - head) : 0;
    int tc = (int)(avail / per_t);
    if (tc > T_) tc = T_;
    if (tc < 1)  tc = 1;
    int nch = (T_ + tc - 1) / tc;
    tc = (T_ + nch - 1) / nch;

    hipLaunchKernelGGL(prep_whh4, dim3(12), dim3(256), 0, stream, Whh, Wprep);
    for (int t0 = 0; t0 < T_; t0 += tc) {
        int len = (T_ - t0 < tc) ? (T_ - t0) : tc;
        hipLaunchKernelGGL(gemm_gi, dim3(len, 2), dim3(256), 0, stream,
                           x, Wih, bih, gi, t0);
        const float* hi = (t0 == 0) ? h0 : h_carry;
        hipLaunchKernelGGL(rec_step, dim3(64), dim3(1024), 0, stream,
                           Wprep, bhh, gi, hi, out, hN, h_carry, t0, len);
    }
}